// Round 15
// baseline (355.471 us; speedup 1.0000x reference)
//
#include <hip/hip_runtime.h>
#include <hip/hip_fp16.h>
#include <math.h>

#define CIN   32
#define CMID  64
#define HH    256
#define WW    256
#define EPSBN 1e-5f
#define ELU_A 0.1f

typedef _Float16 half8 __attribute__((ext_vector_type(8)));
typedef _Float16 half2v __attribute__((ext_vector_type(2)));
typedef float    floatx4 __attribute__((ext_vector_type(4)));

#if __has_builtin(__builtin_amdgcn_fdot2)
#define DOT2(a, b, c) __builtin_amdgcn_fdot2((a), (b), (c), false)
#else
#define DOT2(a, b, c) ((c) + (float)(a)[0] * (float)(b)[0] + (float)(a)[1] * (float)(b)[1])
#endif

__device__ __forceinline__ float elu_f(float x) {
    return x > 0.f ? x : ELU_A * (__expf(x) - 1.f);
}
__device__ __forceinline__ float wave_sum64(float v) {
#pragma unroll
    for (int off = 32; off > 0; off >>= 1) v += __shfl_xor(v, off, 64);
    return v;
}

// ---------------- one-shot prep: cnt zero + weight swizzles + attn consts ----------------
// Slot layout in wlin: 0=gcn, 1=q, 2=skip, 3=k, 4=v
__global__ void prep_all(const float* __restrict__ cw,
                         const float* __restrict__ g2, const float* __restrict__ b2,
                         const float* __restrict__ m2, const float* __restrict__ v2,
                         const float* __restrict__ w_gcn, const float* __restrict__ w_q,
                         const float* __restrict__ w_skip, const float* __restrict__ w_k,
                         const float* __restrict__ w_v,
                         const float* __restrict__ g1, const float* __restrict__ b1,
                         const float* __restrict__ m1, const float* __restrict__ v1,
                         const float* __restrict__ wl, const float* __restrict__ bl,
                         const float* __restrict__ we,
                         __half* __restrict__ wt16, float* __restrict__ ebias,
                         __half* __restrict__ wlin, float* __restrict__ wls,
                         float* __restrict__ consts, int* __restrict__ cnt, int N) {
    int idx = blockIdx.x * 256 + threadIdx.x;
    if (idx < N) cnt[idx] = 0;
    if (idx < 5 * 2 * 4 * 64 * 8) {          // linear weights -> B-frag order
        int j = idx & 7, lane = (idx >> 3) & 63, rest = idx >> 9;
        int ot = rest & 3, kt = (rest >> 2) & 1, mat = rest >> 3;
        int o = ot * 16 + (lane & 15);
        int k = kt * 32 + (lane >> 4) * 8 + j;
        const float* W = (mat == 0) ? w_gcn : (mat == 1) ? w_q :
                         (mat == 2) ? w_skip : (mat == 3) ? w_k : w_v;
        wlin[idx] = __float2half(W[o * 64 + k]);
    }
    if (idx < 36 * 64 * 8) {                 // conv weights -> B-frag order, BN2 folded
        int j = idx & 7, lane = (idx >> 3) & 63, to = idx >> 9;
        int tap = to >> 2, otile = to & 3;
        int o = otile * 16 + (lane & 15);
        int k = (lane >> 4) * 8 + j;
        float s = g2[o] * rsqrtf(v2[o] + EPSBN);
        wt16[idx] = __float2half(cw[(o * 32 + k) * 9 + tap] * s);
    }
    if (idx < 64) {
        float s = g2[idx] * rsqrtf(v2[idx] + EPSBN);
        ebias[idx] = b2[idx] - m2[idx] * s;
    }
    if (blockIdx.x == 0 && threadIdx.x < 64) {   // attn consts (one wave)
        int c = threadIdx.x;
        float s = g1[c] * rsqrtf(v1[c] + EPSBN);
        float w = wl[c] * s;
        wls[c] = w;
        float p0 = w * we[2 * c];
        float p1 = w * we[2 * c + 1];
        float p2 = wl[c] * (b1[c] - m1[c] * s);
        p0 = wave_sum64(p0);
        p1 = wave_sum64(p1);
        p2 = wave_sum64(p2);
        if (c == 0) { consts[0] = p0; consts[1] = p1; consts[2] = p2 + bl[0]; }
    }
}

// ---------------- CSR build ----------------
__global__ void hist_kernel(const int* __restrict__ col, int* __restrict__ cnt,
                            unsigned short* __restrict__ rank, int E) {
    int e = blockIdx.x * 256 + threadIdx.x;
    if (e < E) rank[e] = (unsigned short)atomicAdd(&cnt[col[e]], 1);
}

__global__ void scan1(const int* __restrict__ cnt, int* __restrict__ bsum) {
    __shared__ int s[256];
    int t = threadIdx.x;
    int4 c = reinterpret_cast<const int4*>(cnt)[blockIdx.x * 256 + t];
    s[t] = c.x + c.y + c.z + c.w;
    __syncthreads();
    for (int off = 128; off > 0; off >>= 1) {
        if (t < off) s[t] += s[t + off];
        __syncthreads();
    }
    if (t == 0) bsum[blockIdx.x] = s[0];
}

// merged scan2+scan3: each block reduces the block-sums below it for its own offset,
// then does the intra-block exclusive scan of cnt and writes rowptr.
__global__ void scan23(const int* __restrict__ cnt, const int* __restrict__ bsum,
                       int* __restrict__ rowptr, int Ntot, int nb) {
    __shared__ int red[256];
    __shared__ int lds[256];
    int t = threadIdx.x;
    red[t] = (t < nb && t < blockIdx.x) ? bsum[t] : 0;
    __syncthreads();
    for (int off = 128; off > 0; off >>= 1) {
        if (t < off) red[t] += red[t + off];
        __syncthreads();
    }
    const int boffv = red[0];
    __syncthreads();

    int4 c = reinterpret_cast<const int4*>(cnt)[blockIdx.x * 256 + t];
    int s1 = c.x, s2 = s1 + c.y, s3 = s2 + c.z, s4 = s3 + c.w;
    lds[t] = s4;
    __syncthreads();
    for (int off = 1; off < 256; off <<= 1) {
        int v = (t >= off) ? lds[t - off] : 0;
        __syncthreads();
        lds[t] += v;
        __syncthreads();
    }
    int excl = (t > 0 ? lds[t - 1] : 0) + boffv;
    int base = (blockIdx.x * 256 + t) * 4;
    rowptr[base + 0] = excl;
    rowptr[base + 1] = excl + s1;
    rowptr[base + 2] = excl + s2;
    rowptr[base + 3] = excl + s3;
    if (base + 4 == Ntot) rowptr[Ntot] = excl + s4;
}

// atomic-free scatter: one 8-B record per edge {row, half2 weights}
__global__ void scatter_kernel(const int* __restrict__ ei, const float* __restrict__ ew,
                               const unsigned short* __restrict__ rank,
                               const int* __restrict__ rowptr,
                               int2* __restrict__ edges, int E) {
    int e = blockIdx.x * 256 + threadIdx.x;
    if (e >= E) return;
    int c = ei[E + e];
    int pos = rowptr[c] + (int)rank[e];
    if (pos < 0 || pos >= E) return;   // defensive
    __half2 hw = __floats2half2_rn(ew[2 * e], ew[2 * e + 1]);
    int2 pk;
    pk.x = ei[e];
    pk.y = *reinterpret_cast<int*>(&hw);
    edges[pos] = pk;
}

// ---------------- conv3x3 + BN2 + ELU via MFMA, deg/dinv fused ----------------
// fp32 x in (converted in-register); per-16-pixel weighted degree from contiguous CSR.
__global__ __launch_bounds__(256, 2) void conv_mfma(
        const float* __restrict__ x, const __half* __restrict__ wt16,
        const float* __restrict__ ebias,
        const int2* __restrict__ edges, const int* __restrict__ rowptr,
        float* __restrict__ dinv, __half* __restrict__ h0, int ngroups) {
    const int lane = threadIdx.x & 63;
    const int wid  = (blockIdx.x * 256 + threadIdx.x) >> 6;
    const int n16 = lane & 15, quad = lane >> 4;

    half8 bf[36];
#pragma unroll
    for (int t = 0; t < 36; ++t)
        bf[t] = *reinterpret_cast<const half8*>(wt16 + ((size_t)t * 64 + lane) * 8);
    float eb[4];
#pragma unroll
    for (int ot = 0; ot < 4; ++ot) eb[ot] = ebias[ot * 16 + n16];

    for (int gidx = wid * 4; gidx < wid * 4 + 4; ++gidx) {
        if (gidx >= ngroups) return;
        const int br = gidx >> 4;
        const int c0 = (gidx & 15) << 4;
        const int r  = br & (HH - 1);
        const int nbase = br * WW + c0;

        // ---- weighted degree for the wave's 16 pixels (4 lanes per pixel) ----
        const int pix = lane >> 2, part = lane & 3;
        int pr0 = rowptr[nbase + pix];
        int pr1 = rowptr[nbase + pix + 1];
        float s = 0.f;
        for (int e = pr0 + part; e < pr1; e += 4) {
            int wbits = edges[e].y;
            s += __high2float(*reinterpret_cast<__half2*>(&wbits));
        }
        s += __shfl_xor(s, 1, 64);
        s += __shfl_xor(s, 2, 64);
        float dv_pix = rsqrtf(2.f + s);
        if (part == 0) dinv[nbase + pix] = dv_pix;

        floatx4 acc[4] = {{0.f,0.f,0.f,0.f},{0.f,0.f,0.f,0.f},
                          {0.f,0.f,0.f,0.f},{0.f,0.f,0.f,0.f}};
#pragma unroll
        for (int dr = -1; dr <= 1; ++dr) {
            int rr = r + dr;
            if (rr < 0 || rr >= HH) continue;     // wave-uniform
            const float* xrow = x + (size_t)(br + dr) * WW * CIN;
#pragma unroll
            for (int dc = -1; dc <= 1; ++dc) {
                int cc = c0 + n16 + dc;
                half8 a = {};
                if (cc >= 0 && cc < WW) {
                    const float* xp = xrow + cc * CIN + quad * 8;
                    float4 f0 = *reinterpret_cast<const float4*>(xp);
                    float4 f1 = *reinterpret_cast<const float4*>(xp + 4);
                    a[0] = (_Float16)f0.x; a[1] = (_Float16)f0.y;
                    a[2] = (_Float16)f0.z; a[3] = (_Float16)f0.w;
                    a[4] = (_Float16)f1.x; a[5] = (_Float16)f1.y;
                    a[6] = (_Float16)f1.z; a[7] = (_Float16)f1.w;
                }
                const int tap = (dr + 1) * 3 + (dc + 1);
#pragma unroll
                for (int ot = 0; ot < 4; ++ot)
                    acc[ot] = __builtin_amdgcn_mfma_f32_16x16x32_f16(a, bf[tap * 4 + ot], acc[ot], 0, 0, 0);
            }
        }
        float dv[4];
#pragma unroll
        for (int reg = 0; reg < 4; ++reg)
            dv[reg] = __shfl(dv_pix, (quad * 4 + reg) * 4, 64);
        __half* hp = h0 + (size_t)nbase * 64;
#pragma unroll
        for (int ot = 0; ot < 4; ++ot) {
#pragma unroll
            for (int reg = 0; reg < 4; ++reg) {
                int px = quad * 4 + reg;
                float val = elu_f(acc[ot][reg] + eb[ot]) * dv[reg];
                hp[(size_t)px * 64 + ot * 16 + n16] = __float2half(val);
            }
        }
    }
}

// ---------------- GCN gather: 8 edges/wave, 8 lanes/edge, 8 channels/lane -> fp16 ----------------
__global__ __launch_bounds__(256) void gcn_gather(
        const __half* __restrict__ h0s, const int2* __restrict__ edges,
        const int* __restrict__ rowptr,
        const float* __restrict__ dinv, __half* __restrict__ agg16, int Ntot) {
    const int lane = threadIdx.x & 63;
    const int grp = lane >> 3, t = lane & 7;
    const int n = blockIdx.x * 4 + (threadIdx.x >> 6);
    if (n >= Ntot) return;
    const float din = dinv[n];
    float acc[8] = {0.f,0.f,0.f,0.f,0.f,0.f,0.f,0.f};
    if (grp == 0) {
        half8 hs = *reinterpret_cast<const half8*>(h0s + (size_t)n * 64 + 8 * t);
#pragma unroll
        for (int c = 0; c < 8; ++c) acc[c] = 2.f * din * (float)hs[c];
    }
    const int p0 = rowptr[n], p1 = rowptr[n + 1];
    int p = p0;
    for (; p + 8 <= p1; p += 8) {                 // full batches: no masking
        int2 epk = edges[p + grp];
        int wbits = epk.y;
        float w1 = __high2float(*reinterpret_cast<__half2*>(&wbits));
        float coef = w1 * din;
        half8 hv = *reinterpret_cast<const half8*>(h0s + (size_t)epk.x * 64 + 8 * t);
#pragma unroll
        for (int c = 0; c < 8; ++c) acc[c] = fmaf(coef, (float)hv[c], acc[c]);
    }
    if (p < p1) {                                  // tail batch: masked
        int pe = p + grp;
        bool act = pe < p1;
        int2 epk = edges[act ? pe : p0];
        int wbits = epk.y;
        float w1 = __high2float(*reinterpret_cast<__half2*>(&wbits));
        float coef = act ? w1 * din : 0.f;
        half8 hv = *reinterpret_cast<const half8*>(h0s + (size_t)epk.x * 64 + 8 * t);
#pragma unroll
        for (int c = 0; c < 8; ++c) acc[c] = fmaf(coef, (float)hv[c], acc[c]);
    }
#pragma unroll
    for (int off = 8; off <= 32; off <<= 1) {
#pragma unroll
        for (int c = 0; c < 8; ++c) acc[c] += __shfl_xor(acc[c], off, 64);
    }
    if (grp == 0) {
        half8 ov;
#pragma unroll
        for (int c = 0; c < 8; ++c) ov[c] = (_Float16)acc[c];
        *reinterpret_cast<half8*>(agg16 + (size_t)n * 64 + 8 * t) = ov;
    }
}

// ---------------- FUSED: agg16 -> h1 (LDS) -> q/skip/k/v + per-node aux ----------------
#define LDS_STRIDE 72   // 64 + 8 halves pad (bank-conflict mitigation)
__global__ __launch_bounds__(256) void mfma_fused(
        const __half* __restrict__ in16, const __half* __restrict__ wb,   // slots 0..4
        const float* __restrict__ gcn_b, const float* __restrict__ g,
        const float* __restrict__ b, const float* __restrict__ m,
        const float* __restrict__ v,
        const float* __restrict__ bq, const float* __restrict__ bs,
        const float* __restrict__ bk, const float* __restrict__ bv,
        const float* __restrict__ wls, const float* __restrict__ we,
        __half* __restrict__ qout, __half* __restrict__ kv,
        float4* __restrict__ aux, int ngroups) {
    __shared__ _Float16 lds_h1[4][16 * LDS_STRIDE];
    const int lane = threadIdx.x & 63;
    const int n16 = lane & 15, quad = lane >> 4;
    const int wv_ = threadIdx.x >> 6;
    _Float16* myld = lds_h1[wv_];

    half8 bf1[2][4];
#pragma unroll
    for (int kt = 0; kt < 2; ++kt)
#pragma unroll
        for (int ot = 0; ot < 4; ++ot)
            bf1[kt][ot] = *reinterpret_cast<const half8*>(wb + (((size_t)kt * 4 + ot) * 64 + lane) * 8);
    half8 bf2[4][2][4];
#pragma unroll
    for (int mt = 0; mt < 4; ++mt)
#pragma unroll
        for (int kt = 0; kt < 2; ++kt)
#pragma unroll
            for (int ot = 0; ot < 4; ++ot)
                bf2[mt][kt][ot] = *reinterpret_cast<const half8*>(
                    wb + ((((size_t)(mt + 1) * 2 + kt) * 4 + ot) * 64 + lane) * 8);

    float scl[4], shf[4], bbq[4], bbs[4], bbk[4], bbv[4], wlsv[4], we0v[4], we1v[4];
#pragma unroll
    for (int ot = 0; ot < 4; ++ot) {
        int o = ot * 16 + n16;
        float s = g[o] * rsqrtf(v[o] + EPSBN);
        scl[ot] = s;
        shf[ot] = (gcn_b[o] - m[o]) * s + b[o];
        bbq[ot] = bq[o]; bbs[ot] = bs[o]; bbk[ot] = bk[o]; bbv[ot] = bv[o];
        wlsv[ot] = wls[o];
        we0v[ot] = we[2 * o]; we1v[ot] = we[2 * o + 1];
    }

    const int wid    = blockIdx.x * 4 + wv_;
    const int stride = gridDim.x * 4;
    const int trips  = (ngroups + stride - 1) / stride;
    for (int it = 0; it < trips; ++it) {
        const int gi = wid + it * stride;
        const bool active = gi < ngroups;
        const int nbase = gi * 16;
        if (active) {
            half8 a0 = *reinterpret_cast<const half8*>(in16 + (size_t)(nbase + n16) * 64 + quad * 8);
            half8 a1 = *reinterpret_cast<const half8*>(in16 + (size_t)(nbase + n16) * 64 + 32 + quad * 8);
            floatx4 acc[4] = {{0,0,0,0},{0,0,0,0},{0,0,0,0},{0,0,0,0}};
#pragma unroll
            for (int ot = 0; ot < 4; ++ot) {
                acc[ot] = __builtin_amdgcn_mfma_f32_16x16x32_f16(a0, bf1[0][ot], acc[ot], 0, 0, 0);
                acc[ot] = __builtin_amdgcn_mfma_f32_16x16x32_f16(a1, bf1[1][ot], acc[ot], 0, 0, 0);
            }
#pragma unroll
            for (int ot = 0; ot < 4; ++ot)
#pragma unroll
                for (int reg = 0; reg < 4; ++reg) {
                    float val = elu_f(acc[ot][reg] * scl[ot] + shf[ot]);
                    myld[(quad * 4 + reg) * LDS_STRIDE + ot * 16 + n16] = (_Float16)val;
                }
        }
        __syncthreads();
        if (active) {
            half8 c0 = *reinterpret_cast<const half8*>(&myld[n16 * LDS_STRIDE + quad * 8]);
            half8 c1 = *reinterpret_cast<const half8*>(&myld[n16 * LDS_STRIDE + 32 + quad * 8]);
            floatx4 aq[4] = {{0,0,0,0},{0,0,0,0},{0,0,0,0},{0,0,0,0}};
            floatx4 as[4] = {{0,0,0,0},{0,0,0,0},{0,0,0,0},{0,0,0,0}};
            floatx4 ak[4] = {{0,0,0,0},{0,0,0,0},{0,0,0,0},{0,0,0,0}};
            floatx4 av[4] = {{0,0,0,0},{0,0,0,0},{0,0,0,0},{0,0,0,0}};
#pragma unroll
            for (int ot = 0; ot < 4; ++ot) {
                aq[ot] = __builtin_amdgcn_mfma_f32_16x16x32_f16(c0, bf2[0][0][ot], aq[ot], 0, 0, 0);
                aq[ot] = __builtin_amdgcn_mfma_f32_16x16x32_f16(c1, bf2[0][1][ot], aq[ot], 0, 0, 0);
                as[ot] = __builtin_amdgcn_mfma_f32_16x16x32_f16(c0, bf2[1][0][ot], as[ot], 0, 0, 0);
                as[ot] = __builtin_amdgcn_mfma_f32_16x16x32_f16(c1, bf2[1][1][ot], as[ot], 0, 0, 0);
                ak[ot] = __builtin_amdgcn_mfma_f32_16x16x32_f16(c0, bf2[2][0][ot], ak[ot], 0, 0, 0);
                ak[ot] = __builtin_amdgcn_mfma_f32_16x16x32_f16(c1, bf2[2][1][ot], ak[ot], 0, 0, 0);
                av[ot] = __builtin_amdgcn_mfma_f32_16x16x32_f16(c0, bf2[3][0][ot], av[ot], 0, 0, 0);
                av[ot] = __builtin_amdgcn_mfma_f32_16x16x32_f16(c1, bf2[3][1][ot], av[ot], 0, 0, 0);
            }
            float psd[4] = {0,0,0,0}, pq0[4] = {0,0,0,0}, pq1[4] = {0,0,0,0};
#pragma unroll
            for (int ot = 0; ot < 4; ++ot)
#pragma unroll
                for (int reg = 0; reg < 4; ++reg) {
                    int px = nbase + quad * 4 + reg;
                    size_t off64  = (size_t)px * 64 + ot * 16 + n16;
                    size_t off128 = (size_t)px * 128 + ot * 16 + n16;
                    float qv = aq[ot][reg] + bbq[ot];
                    qout[off64]    = __float2half(qv);
                    kv[off128]     = __float2half(ak[ot][reg] + bbk[ot]);
                    kv[off128+64]  = __float2half(av[ot][reg] + bbv[ot]);
                    psd[reg] = fmaf(wlsv[ot], as[ot][reg] + bbs[ot], psd[reg]);
                    pq0[reg] = fmaf(we0v[ot], qv, pq0[reg]);
                    pq1[reg] = fmaf(we1v[ot], qv, pq1[reg]);
                }
#pragma unroll
            for (int off = 1; off <= 8; off <<= 1)
#pragma unroll
                for (int reg = 0; reg < 4; ++reg) {
                    psd[reg] += __shfl_xor(psd[reg], off, 64);
                    pq0[reg] += __shfl_xor(pq0[reg], off, 64);
                    pq1[reg] += __shfl_xor(pq1[reg], off, 64);
                }
            if (n16 == 0) {
#pragma unroll
                for (int reg = 0; reg < 4; ++reg)
                    aux[nbase + quad * 4 + reg] =
                        make_float4(pq0[reg], pq1[reg], psd[reg], 0.f);
            }
        }
        __syncthreads();
    }
}

// ---------------- fused attention: 8 edges/wave, 8 lanes/edge, 8 channels/lane ----------------
// No online max: |alpha| is O(1) here (0.05-scale weights); softmax is shift-invariant.
__global__ __launch_bounds__(256) void attn_out(
        const __half* __restrict__ qh, const __half* __restrict__ kv,
        const float4* __restrict__ aux,
        const int2* __restrict__ edges, const int* __restrict__ rowptr,
        const float* __restrict__ wls, const float* __restrict__ consts,
        float* __restrict__ out, int Ntot) {
    const int lane = threadIdx.x & 63;
    const int grp = lane >> 3, t = lane & 7;
    const int n = blockIdx.x * 4 + (threadIdx.x >> 6);
    if (n >= Ntot) return;

    half8 q8 = *reinterpret_cast<const half8*>(qh + (size_t)n * 64 + 8 * t);
    half2v q2[4];
#pragma unroll
    for (int i = 0; i < 4; ++i) { q2[i][0] = q8[2 * i]; q2[i][1] = q8[2 * i + 1]; }
    float4 ax = aux[n];                 // {qe0, qe1, skipdot, -}
    const float qe0 = ax.x, qe1 = ax.y;

    const int p0 = rowptr[n], p1 = rowptr[n + 1];
    float l = 0.f, sx = 0.f, sy = 0.f;
    float acc[8] = {0.f,0.f,0.f,0.f,0.f,0.f,0.f,0.f};
    int p = p0;
    for (; p + 8 <= p1; p += 8) {                 // full batches: no masking
        int2 epk = edges[p + grp];
        int wbits = epk.y;
        float2 w = __half22float2(*reinterpret_cast<__half2*>(&wbits));
        const __half* kvp = kv + (size_t)epk.x * 128 + 8 * t;
        half8 k8 = *reinterpret_cast<const half8*>(kvp);
        half8 v8 = *reinterpret_cast<const half8*>(kvp + 64);
        const half2v* k2 = reinterpret_cast<const half2v*>(&k8);
        float prod = 0.f;
#pragma unroll
        for (int i = 0; i < 4; ++i) prod = DOT2(q2[i], k2[i], prod);
#pragma unroll
        for (int off = 1; off <= 4; off <<= 1) prod += __shfl_xor(prod, off, 64);
        float ex = __expf(fmaf(qe0, w.x, fmaf(qe1, w.y, prod)) * 0.125f);
        l += ex;
        sx = fmaf(ex, w.x, sx);
        sy = fmaf(ex, w.y, sy);
#pragma unroll
        for (int c = 0; c < 8; ++c) acc[c] = fmaf(ex, (float)v8[c], acc[c]);
    }
    if (p < p1) {                                  // tail batch: masked
        int pe = p + grp;
        bool act = pe < p1;
        int2 epk = edges[act ? pe : p0];
        int wbits = epk.y;
        float2 w = __half22float2(*reinterpret_cast<__half2*>(&wbits));
        const __half* kvp = kv + (size_t)epk.x * 128 + 8 * t;
        half8 k8 = *reinterpret_cast<const half8*>(kvp);
        half8 v8 = *reinterpret_cast<const half8*>(kvp + 64);
        const half2v* k2 = reinterpret_cast<const half2v*>(&k8);
        float prod = 0.f;
#pragma unroll
        for (int i = 0; i < 4; ++i) prod = DOT2(q2[i], k2[i], prod);
#pragma unroll
        for (int off = 1; off <= 4; off <<= 1) prod += __shfl_xor(prod, off, 64);
        float ex = act ? __expf(fmaf(qe0, w.x, fmaf(qe1, w.y, prod)) * 0.125f) : 0.f;
        l += ex;
        sx = fmaf(ex, w.x, sx);
        sy = fmaf(ex, w.y, sy);
#pragma unroll
        for (int c = 0; c < 8; ++c) acc[c] = fmaf(ex, (float)v8[c], acc[c]);
    }
    float4 wlsA = reinterpret_cast<const float4*>(wls)[2 * t];
    float4 wlsB = reinterpret_cast<const float4*>(wls)[2 * t + 1];
    float pd = acc[0] * wlsA.x + acc[1] * wlsA.y + acc[2] * wlsA.z + acc[3] * wlsA.w
             + acc[4] * wlsB.x + acc[5] * wlsB.y + acc[6] * wlsB.z + acc[7] * wlsB.w;
#pragma unroll
    for (int off = 1; off <= 32; off <<= 1) pd += __shfl_xor(pd, off, 64);
#pragma unroll
    for (int off = 8; off <= 32; off <<= 1) {      // across groups only
        l  += __shfl_xor(l,  off, 64);
        sx += __shfl_xor(sx, off, 64);
        sy += __shfl_xor(sy, off, 64);
    }
    if (lane == 0) {
        float inv_l = (l > 0.f) ? 1.f / l : 0.f;
        out[n] = inv_l * (pd + sx * consts[0] + sy * consts[1]) + ax.z + consts[2];
    }
}

// ---------------- launcher ----------------
extern "C" void kernel_launch(void* const* d_in, const int* in_sizes, int n_in,
                              void* d_out, int out_size, void* d_ws, size_t ws_size,
                              hipStream_t stream) {
    const float* x      = (const float*)d_in[0];
    const int*   ei     = (const int*)d_in[1];
    const float* ew     = (const float*)d_in[2];
    const float* conv_w = (const float*)d_in[6];
    const float* bn2_g  = (const float*)d_in[7];
    const float* bn2_b  = (const float*)d_in[8];
    const float* bn2_m  = (const float*)d_in[9];
    const float* bn2_v  = (const float*)d_in[10];
    const float* gcn_w  = (const float*)d_in[11];
    const float* gcn_b  = (const float*)d_in[12];
    const float* bn1_g  = (const float*)d_in[13];
    const float* bn1_b  = (const float*)d_in[14];
    const float* bn1_m  = (const float*)d_in[15];
    const float* bn1_v  = (const float*)d_in[16];
    const float* wq     = (const float*)d_in[17];
    const float* bq     = (const float*)d_in[18];
    const float* wk     = (const float*)d_in[19];
    const float* bk     = (const float*)d_in[20];
    const float* wv     = (const float*)d_in[21];
    const float* bv     = (const float*)d_in[22];
    const float* we     = (const float*)d_in[23];
    const float* wskip  = (const float*)d_in[24];
    const float* bskip  = (const float*)d_in[25];
    const float* wl     = (const float*)d_in[26];
    const float* bl     = (const float*)d_in[27];

    const int N = in_sizes[0] / CIN;     // 131072
    const int E = in_sizes[1] / 2;       // 1048576

    char* p = (char*)d_ws;
    auto alloc = [&](size_t bytes) {
        void* r = (void*)p;
        p += (bytes + 255) & ~(size_t)255;
        return r;
    };
    __half* wt16    = (__half*)alloc(36 * 64 * 8 * 2);
    float*  ebias   = (float*)alloc(64 * 4);
    __half* wlin    = (__half*)alloc(5 * 2 * 4 * 64 * 8 * 2);
    float*  wls     = (float*)alloc(64 * 4);
    float*  consts  = (float*)alloc(64 * 4);
    __half* bufA    = (__half*)alloc((size_t)N * 64 * 2);      // h0s fp16
    float*  bufB    = (float*)alloc((size_t)N * 64 * 4);       // kv fp16
    __half* bufQ    = (__half*)alloc((size_t)N * 64 * 2);      // q fp16
    __half* agg16   = (__half*)alloc((size_t)N * 64 * 2);      // agg fp16
    float4* aux     = (float4*)alloc((size_t)N * 16);          // {qe0,qe1,skipdot}
    float*  dinv    = (float*)alloc((size_t)N * 4);
    int*    cnt     = (int*)alloc((size_t)N * 4);
    unsigned short* rank = (unsigned short*)alloc((size_t)E * 2);
    int*    rowptr  = (int*)alloc((size_t)(N + 1) * 4);
    int2*   edges   = (int2*)alloc((size_t)E * 8);             // {row, half2 w}
    int*    bsum    = (int*)alloc(256 * 4);

    __half* kv = (__half*)bufB;

    // ---- one-shot prep (cnt zero + all weight swizzles + attn consts) ----
    prep_all<<<(N + 255) / 256, 256, 0, stream>>>(
        conv_w, bn2_g, bn2_b, bn2_m, bn2_v,
        gcn_w, wq, wskip, wk, wv,
        bn1_g, bn1_b, bn1_m, bn1_v, wl, bl, we,
        wt16, ebias, wlin, wls, consts, cnt, N);

    // ---- CSR build ----
    hist_kernel<<<(E + 255) / 256, 256, 0, stream>>>(ei + E, cnt, rank, E);
    scan1<<<N / 1024, 256, 0, stream>>>(cnt, bsum);
    scan23<<<N / 1024, 256, 0, stream>>>(cnt, bsum, rowptr, N, N / 1024);
    scatter_kernel<<<(E + 255) / 256, 256, 0, stream>>>(ei, ew, rank, rowptr, edges, E);

    const int ngroups = N / 16;
    // conv + fused weighted-degree/dinv
    conv_mfma<<<ngroups / 16, 256, 0, stream>>>(x, wt16, ebias, edges, rowptr,
                                                dinv, bufA, ngroups);

    gcn_gather<<<(N + 3) / 4, 256, 0, stream>>>(bufA, edges, rowptr, dinv, agg16, N);

    mfma_fused<<<512, 256, 0, stream>>>(agg16, wlin, gcn_b,
                                        bn1_g, bn1_b, bn1_m, bn1_v,
                                        bq, bskip, bk, bv, wls, we,
                                        bufQ, kv, aux, ngroups);

    attn_out<<<(N + 3) / 4, 256, 0, stream>>>(bufQ, kv, aux, edges, rowptr,
                                              wls, consts, (float*)d_out, N);
}

// Round 16
// 351.669 us; speedup vs baseline: 1.0108x; 1.0108x over previous
//
#include <hip/hip_runtime.h>
#include <hip/hip_fp16.h>
#include <math.h>

#define CIN   32
#define CMID  64
#define HH    256
#define WW    256
#define EPSBN 1e-5f
#define ELU_A 0.1f

typedef _Float16 half8 __attribute__((ext_vector_type(8)));
typedef _Float16 half2v __attribute__((ext_vector_type(2)));
typedef float    floatx4 __attribute__((ext_vector_type(4)));

#if __has_builtin(__builtin_amdgcn_fdot2)
#define DOT2(a, b, c) __builtin_amdgcn_fdot2((a), (b), (c), false)
#else
#define DOT2(a, b, c) ((c) + (float)(a)[0] * (float)(b)[0] + (float)(a)[1] * (float)(b)[1])
#endif

__device__ __forceinline__ float elu_f(float x) {
    return x > 0.f ? x : ELU_A * (__expf(x) - 1.f);
}
__device__ __forceinline__ float wave_sum64(float v) {
#pragma unroll
    for (int off = 32; off > 0; off >>= 1) v += __shfl_xor(v, off, 64);
    return v;
}

// ---------------- one-shot prep: cnt zero + weight swizzles + attn consts ----------------
// Slot layout in wlin: 0=gcn, 1=q, 2=skip, 3=k, 4=v
__global__ void prep_all(const float* __restrict__ cw,
                         const float* __restrict__ g2, const float* __restrict__ b2,
                         const float* __restrict__ m2, const float* __restrict__ v2,
                         const float* __restrict__ w_gcn, const float* __restrict__ w_q,
                         const float* __restrict__ w_skip, const float* __restrict__ w_k,
                         const float* __restrict__ w_v,
                         const float* __restrict__ g1, const float* __restrict__ b1,
                         const float* __restrict__ m1, const float* __restrict__ v1,
                         const float* __restrict__ wl, const float* __restrict__ bl,
                         const float* __restrict__ we,
                         __half* __restrict__ wt16, float* __restrict__ ebias,
                         __half* __restrict__ wlin, float* __restrict__ wls,
                         float* __restrict__ consts, int* __restrict__ cnt, int N) {
    int idx = blockIdx.x * 256 + threadIdx.x;
    if (idx < N) cnt[idx] = 0;
    if (idx < 5 * 2 * 4 * 64 * 8) {          // linear weights -> B-frag order
        int j = idx & 7, lane = (idx >> 3) & 63, rest = idx >> 9;
        int ot = rest & 3, kt = (rest >> 2) & 1, mat = rest >> 3;
        int o = ot * 16 + (lane & 15);
        int k = kt * 32 + (lane >> 4) * 8 + j;
        const float* W = (mat == 0) ? w_gcn : (mat == 1) ? w_q :
                         (mat == 2) ? w_skip : (mat == 3) ? w_k : w_v;
        wlin[idx] = __float2half(W[o * 64 + k]);
    }
    if (idx < 36 * 64 * 8) {                 // conv weights -> B-frag order, BN2 folded
        int j = idx & 7, lane = (idx >> 3) & 63, to = idx >> 9;
        int tap = to >> 2, otile = to & 3;
        int o = otile * 16 + (lane & 15);
        int k = (lane >> 4) * 8 + j;
        float s = g2[o] * rsqrtf(v2[o] + EPSBN);
        wt16[idx] = __float2half(cw[(o * 32 + k) * 9 + tap] * s);
    }
    if (idx < 64) {
        float s = g2[idx] * rsqrtf(v2[idx] + EPSBN);
        ebias[idx] = b2[idx] - m2[idx] * s;
    }
    if (blockIdx.x == 0 && threadIdx.x < 64) {   // attn consts (one wave)
        int c = threadIdx.x;
        float s = g1[c] * rsqrtf(v1[c] + EPSBN);
        float w = wl[c] * s;
        wls[c] = w;
        float p0 = w * we[2 * c];
        float p1 = w * we[2 * c + 1];
        float p2 = wl[c] * (b1[c] - m1[c] * s);
        p0 = wave_sum64(p0);
        p1 = wave_sum64(p1);
        p2 = wave_sum64(p2);
        if (c == 0) { consts[0] = p0; consts[1] = p1; consts[2] = p2 + bl[0]; }
    }
}

// ---------------- conv3x3 + BN2 + ELU via MFMA (fp32 x in, converted in-register) ----------------
__global__ __launch_bounds__(256, 2) void conv_mfma(
        const float* __restrict__ x, const __half* __restrict__ wt16,
        const float* __restrict__ ebias, const float* __restrict__ dinv,
        __half* __restrict__ h0, int ngroups) {
    const int lane = threadIdx.x & 63;
    const int wid  = (blockIdx.x * 256 + threadIdx.x) >> 6;
    const int n16 = lane & 15, quad = lane >> 4;

    half8 bf[36];
#pragma unroll
    for (int t = 0; t < 36; ++t)
        bf[t] = *reinterpret_cast<const half8*>(wt16 + ((size_t)t * 64 + lane) * 8);
    float eb[4];
#pragma unroll
    for (int ot = 0; ot < 4; ++ot) eb[ot] = ebias[ot * 16 + n16];

    for (int gidx = wid * 4; gidx < wid * 4 + 4; ++gidx) {
        if (gidx >= ngroups) return;
        const int br = gidx >> 4;
        const int c0 = (gidx & 15) << 4;
        const int r  = br & (HH - 1);
        floatx4 acc[4] = {{0.f,0.f,0.f,0.f},{0.f,0.f,0.f,0.f},
                          {0.f,0.f,0.f,0.f},{0.f,0.f,0.f,0.f}};
#pragma unroll
        for (int dr = -1; dr <= 1; ++dr) {
            int rr = r + dr;
            if (rr < 0 || rr >= HH) continue;     // wave-uniform
            const float* xrow = x + (size_t)(br + dr) * WW * CIN;
#pragma unroll
            for (int dc = -1; dc <= 1; ++dc) {
                int cc = c0 + n16 + dc;
                half8 a = {};
                if (cc >= 0 && cc < WW) {
                    const float* xp = xrow + cc * CIN + quad * 8;
                    float4 f0 = *reinterpret_cast<const float4*>(xp);
                    float4 f1 = *reinterpret_cast<const float4*>(xp + 4);
                    a[0] = (_Float16)f0.x; a[1] = (_Float16)f0.y;
                    a[2] = (_Float16)f0.z; a[3] = (_Float16)f0.w;
                    a[4] = (_Float16)f1.x; a[5] = (_Float16)f1.y;
                    a[6] = (_Float16)f1.z; a[7] = (_Float16)f1.w;
                }
                const int tap = (dr + 1) * 3 + (dc + 1);
#pragma unroll
                for (int ot = 0; ot < 4; ++ot)
                    acc[ot] = __builtin_amdgcn_mfma_f32_16x16x32_f16(a, bf[tap * 4 + ot], acc[ot], 0, 0, 0);
            }
        }
        const int nbase = br * WW + c0;
        float dv[4];
#pragma unroll
        for (int reg = 0; reg < 4; ++reg) dv[reg] = dinv[nbase + quad * 4 + reg];
        __half* hp = h0 + (size_t)nbase * 64;
#pragma unroll
        for (int ot = 0; ot < 4; ++ot) {
#pragma unroll
            for (int reg = 0; reg < 4; ++reg) {
                int px = quad * 4 + reg;
                float val = elu_f(acc[ot][reg] + eb[ot]) * dv[reg];
                hp[(size_t)px * 64 + ot * 16 + n16] = __float2half(val);
            }
        }
    }
}

// ---------------- CSR build ----------------
__global__ void hist_kernel(const int* __restrict__ col, int* __restrict__ cnt,
                            unsigned short* __restrict__ rank, int E) {
    int e = blockIdx.x * 256 + threadIdx.x;
    if (e < E) rank[e] = (unsigned short)atomicAdd(&cnt[col[e]], 1);
}

__global__ void scan1(const int* __restrict__ cnt, int* __restrict__ bsum) {
    __shared__ int s[256];
    int t = threadIdx.x;
    int4 c = reinterpret_cast<const int4*>(cnt)[blockIdx.x * 256 + t];
    s[t] = c.x + c.y + c.z + c.w;
    __syncthreads();
    for (int off = 128; off > 0; off >>= 1) {
        if (t < off) s[t] += s[t + off];
        __syncthreads();
    }
    if (t == 0) bsum[blockIdx.x] = s[0];
}

// one wave, nb <= 128: shfl prefix scan
__global__ void scan2(const int* __restrict__ bsum, int* __restrict__ boff, int nb) {
    int t = threadIdx.x;   // 64 threads
    int b0 = (t < nb) ? bsum[t] : 0;
    int b1 = (t + 64 < nb) ? bsum[t + 64] : 0;
    int v0 = b0, v1 = b1;
#pragma unroll
    for (int off = 1; off < 64; off <<= 1) {
        int u0 = __shfl_up(v0, off, 64);
        int u1 = __shfl_up(v1, off, 64);
        if (t >= off) { v0 += u0; v1 += u1; }
    }
    int tot0 = __shfl(v0, 63, 64);
    if (t < nb) boff[t] = v0 - b0;
    if (t + 64 < nb) boff[t + 64] = tot0 + v1 - b1;
}

__global__ void scan3(const int* __restrict__ cnt, const int* __restrict__ boff,
                      int* __restrict__ rowptr, int Ntot) {
    __shared__ int lds[256];
    int t = threadIdx.x;
    int4 c = reinterpret_cast<const int4*>(cnt)[blockIdx.x * 256 + t];
    int s1 = c.x, s2 = s1 + c.y, s3 = s2 + c.z, s4 = s3 + c.w;
    lds[t] = s4;
    __syncthreads();
    for (int off = 1; off < 256; off <<= 1) {
        int v = (t >= off) ? lds[t - off] : 0;
        __syncthreads();
        lds[t] += v;
        __syncthreads();
    }
    int excl = (t > 0 ? lds[t - 1] : 0) + boff[blockIdx.x];
    int base = (blockIdx.x * 256 + t) * 4;
    rowptr[base + 0] = excl;
    rowptr[base + 1] = excl + s1;
    rowptr[base + 2] = excl + s2;
    rowptr[base + 3] = excl + s3;
    if (base + 4 == Ntot) rowptr[Ntot] = excl + s4;
}

// atomic-free scatter: one 8-B record per edge {row, half2 weights}
__global__ void scatter_kernel(const int* __restrict__ ei, const float* __restrict__ ew,
                               const unsigned short* __restrict__ rank,
                               const int* __restrict__ rowptr,
                               int2* __restrict__ edges, int E) {
    int e = blockIdx.x * 256 + threadIdx.x;
    if (e >= E) return;
    int c = ei[E + e];
    int pos = rowptr[c] + (int)rank[e];
    if (pos < 0 || pos >= E) return;   // defensive
    __half2 hw = __floats2half2_rn(ew[2 * e], ew[2 * e + 1]);
    int2 pk;
    pk.x = ei[e];
    pk.y = *reinterpret_cast<int*>(&hw);
    edges[pos] = pk;
}

// ---------------- degree / dinv (contiguous edge-record scan) ----------------
__global__ void deg_kernel(const int* __restrict__ rowptr, const int2* __restrict__ edges,
                           float* __restrict__ dinv, int Ntot) {
    int n = blockIdx.x * 256 + threadIdx.x;
    if (n >= Ntot) return;
    int p0 = rowptr[n], p1 = rowptr[n + 1];
    float s = 2.f;                  // self loop weight
    for (int p = p0; p < p1; ++p) {
        int wbits = edges[p].y;
        s += __high2float(*reinterpret_cast<__half2*>(&wbits));
    }
    dinv[n] = rsqrtf(s);
}

// ---------------- GCN gather: 8 edges/wave, 8 lanes/edge, 8 channels/lane -> fp16 ----------------
__global__ __launch_bounds__(256) void gcn_gather(
        const __half* __restrict__ h0s, const int2* __restrict__ edges,
        const int* __restrict__ rowptr,
        const float* __restrict__ dinv, __half* __restrict__ agg16, int Ntot) {
    const int lane = threadIdx.x & 63;
    const int grp = lane >> 3, t = lane & 7;
    const int n = blockIdx.x * 4 + (threadIdx.x >> 6);
    if (n >= Ntot) return;
    const float din = dinv[n];
    float acc[8] = {0.f,0.f,0.f,0.f,0.f,0.f,0.f,0.f};
    if (grp == 0) {
        half8 hs = *reinterpret_cast<const half8*>(h0s + (size_t)n * 64 + 8 * t);
#pragma unroll
        for (int c = 0; c < 8; ++c) acc[c] = 2.f * din * (float)hs[c];
    }
    const int p0 = rowptr[n], p1 = rowptr[n + 1];
    int p = p0;
    for (; p + 8 <= p1; p += 8) {                 // full batches: no masking
        int2 epk = edges[p + grp];
        int wbits = epk.y;
        float w1 = __high2float(*reinterpret_cast<__half2*>(&wbits));
        float coef = w1 * din;
        half8 hv = *reinterpret_cast<const half8*>(h0s + (size_t)epk.x * 64 + 8 * t);
#pragma unroll
        for (int c = 0; c < 8; ++c) acc[c] = fmaf(coef, (float)hv[c], acc[c]);
    }
    if (p < p1) {                                  // tail batch: masked
        int pe = p + grp;
        bool act = pe < p1;
        int2 epk = edges[act ? pe : p0];
        int wbits = epk.y;
        float w1 = __high2float(*reinterpret_cast<__half2*>(&wbits));
        float coef = act ? w1 * din : 0.f;
        half8 hv = *reinterpret_cast<const half8*>(h0s + (size_t)epk.x * 64 + 8 * t);
#pragma unroll
        for (int c = 0; c < 8; ++c) acc[c] = fmaf(coef, (float)hv[c], acc[c]);
    }
#pragma unroll
    for (int off = 8; off <= 32; off <<= 1) {
#pragma unroll
        for (int c = 0; c < 8; ++c) acc[c] += __shfl_xor(acc[c], off, 64);
    }
    if (grp == 0) {
        half8 ov;
#pragma unroll
        for (int c = 0; c < 8; ++c) ov[c] = (_Float16)acc[c];
        *reinterpret_cast<half8*>(agg16 + (size_t)n * 64 + 8 * t) = ov;
    }
}

// ---------------- FUSED: agg16 -> h1 (LDS) -> q/skip/k/v + per-node aux ----------------
#define LDS_STRIDE 72   // 64 + 8 halves pad (bank-conflict mitigation)
__global__ __launch_bounds__(256) void mfma_fused(
        const __half* __restrict__ in16, const __half* __restrict__ wb,   // slots 0..4
        const float* __restrict__ gcn_b, const float* __restrict__ g,
        const float* __restrict__ b, const float* __restrict__ m,
        const float* __restrict__ v,
        const float* __restrict__ bq, const float* __restrict__ bs,
        const float* __restrict__ bk, const float* __restrict__ bv,
        const float* __restrict__ wls, const float* __restrict__ we,
        __half* __restrict__ qout, __half* __restrict__ kv,
        float4* __restrict__ aux, int ngroups) {
    __shared__ _Float16 lds_h1[4][16 * LDS_STRIDE];
    const int lane = threadIdx.x & 63;
    const int n16 = lane & 15, quad = lane >> 4;
    const int wv_ = threadIdx.x >> 6;
    _Float16* myld = lds_h1[wv_];

    half8 bf1[2][4];
#pragma unroll
    for (int kt = 0; kt < 2; ++kt)
#pragma unroll
        for (int ot = 0; ot < 4; ++ot)
            bf1[kt][ot] = *reinterpret_cast<const half8*>(wb + (((size_t)kt * 4 + ot) * 64 + lane) * 8);
    half8 bf2[4][2][4];
#pragma unroll
    for (int mt = 0; mt < 4; ++mt)
#pragma unroll
        for (int kt = 0; kt < 2; ++kt)
#pragma unroll
            for (int ot = 0; ot < 4; ++ot)
                bf2[mt][kt][ot] = *reinterpret_cast<const half8*>(
                    wb + ((((size_t)(mt + 1) * 2 + kt) * 4 + ot) * 64 + lane) * 8);

    float scl[4], shf[4], bbq[4], bbs[4], bbk[4], bbv[4], wlsv[4], we0v[4], we1v[4];
#pragma unroll
    for (int ot = 0; ot < 4; ++ot) {
        int o = ot * 16 + n16;
        float s = g[o] * rsqrtf(v[o] + EPSBN);
        scl[ot] = s;
        shf[ot] = (gcn_b[o] - m[o]) * s + b[o];
        bbq[ot] = bq[o]; bbs[ot] = bs[o]; bbk[ot] = bk[o]; bbv[ot] = bv[o];
        wlsv[ot] = wls[o];
        we0v[ot] = we[2 * o]; we1v[ot] = we[2 * o + 1];
    }

    const int wid    = blockIdx.x * 4 + wv_;
    const int stride = gridDim.x * 4;
    const int trips  = (ngroups + stride - 1) / stride;
    for (int it = 0; it < trips; ++it) {
        const int gi = wid + it * stride;
        const bool active = gi < ngroups;
        const int nbase = gi * 16;
        if (active) {
            half8 a0 = *reinterpret_cast<const half8*>(in16 + (size_t)(nbase + n16) * 64 + quad * 8);
            half8 a1 = *reinterpret_cast<const half8*>(in16 + (size_t)(nbase + n16) * 64 + 32 + quad * 8);
            floatx4 acc[4] = {{0,0,0,0},{0,0,0,0},{0,0,0,0},{0,0,0,0}};
#pragma unroll
            for (int ot = 0; ot < 4; ++ot) {
                acc[ot] = __builtin_amdgcn_mfma_f32_16x16x32_f16(a0, bf1[0][ot], acc[ot], 0, 0, 0);
                acc[ot] = __builtin_amdgcn_mfma_f32_16x16x32_f16(a1, bf1[1][ot], acc[ot], 0, 0, 0);
            }
#pragma unroll
            for (int ot = 0; ot < 4; ++ot)
#pragma unroll
                for (int reg = 0; reg < 4; ++reg) {
                    float val = elu_f(acc[ot][reg] * scl[ot] + shf[ot]);
                    myld[(quad * 4 + reg) * LDS_STRIDE + ot * 16 + n16] = (_Float16)val;
                }
        }
        __syncthreads();
        if (active) {
            half8 c0 = *reinterpret_cast<const half8*>(&myld[n16 * LDS_STRIDE + quad * 8]);
            half8 c1 = *reinterpret_cast<const half8*>(&myld[n16 * LDS_STRIDE + 32 + quad * 8]);
            floatx4 aq[4] = {{0,0,0,0},{0,0,0,0},{0,0,0,0},{0,0,0,0}};
            floatx4 as[4] = {{0,0,0,0},{0,0,0,0},{0,0,0,0},{0,0,0,0}};
            floatx4 ak[4] = {{0,0,0,0},{0,0,0,0},{0,0,0,0},{0,0,0,0}};
            floatx4 av[4] = {{0,0,0,0},{0,0,0,0},{0,0,0,0},{0,0,0,0}};
#pragma unroll
            for (int ot = 0; ot < 4; ++ot) {
                aq[ot] = __builtin_amdgcn_mfma_f32_16x16x32_f16(c0, bf2[0][0][ot], aq[ot], 0, 0, 0);
                aq[ot] = __builtin_amdgcn_mfma_f32_16x16x32_f16(c1, bf2[0][1][ot], aq[ot], 0, 0, 0);
                as[ot] = __builtin_amdgcn_mfma_f32_16x16x32_f16(c0, bf2[1][0][ot], as[ot], 0, 0, 0);
                as[ot] = __builtin_amdgcn_mfma_f32_16x16x32_f16(c1, bf2[1][1][ot], as[ot], 0, 0, 0);
                ak[ot] = __builtin_amdgcn_mfma_f32_16x16x32_f16(c0, bf2[2][0][ot], ak[ot], 0, 0, 0);
                ak[ot] = __builtin_amdgcn_mfma_f32_16x16x32_f16(c1, bf2[2][1][ot], ak[ot], 0, 0, 0);
                av[ot] = __builtin_amdgcn_mfma_f32_16x16x32_f16(c0, bf2[3][0][ot], av[ot], 0, 0, 0);
                av[ot] = __builtin_amdgcn_mfma_f32_16x16x32_f16(c1, bf2[3][1][ot], av[ot], 0, 0, 0);
            }
            float psd[4] = {0,0,0,0}, pq0[4] = {0,0,0,0}, pq1[4] = {0,0,0,0};
#pragma unroll
            for (int ot = 0; ot < 4; ++ot)
#pragma unroll
                for (int reg = 0; reg < 4; ++reg) {
                    int px = nbase + quad * 4 + reg;
                    size_t off64  = (size_t)px * 64 + ot * 16 + n16;
                    size_t off128 = (size_t)px * 128 + ot * 16 + n16;
                    float qv = aq[ot][reg] + bbq[ot];
                    qout[off64]    = __float2half(qv);
                    kv[off128]     = __float2half(ak[ot][reg] + bbk[ot]);
                    kv[off128+64]  = __float2half(av[ot][reg] + bbv[ot]);
                    psd[reg] = fmaf(wlsv[ot], as[ot][reg] + bbs[ot], psd[reg]);
                    pq0[reg] = fmaf(we0v[ot], qv, pq0[reg]);
                    pq1[reg] = fmaf(we1v[ot], qv, pq1[reg]);
                }
#pragma unroll
            for (int off = 1; off <= 8; off <<= 1)
#pragma unroll
                for (int reg = 0; reg < 4; ++reg) {
                    psd[reg] += __shfl_xor(psd[reg], off, 64);
                    pq0[reg] += __shfl_xor(pq0[reg], off, 64);
                    pq1[reg] += __shfl_xor(pq1[reg], off, 64);
                }
            if (n16 == 0) {
#pragma unroll
                for (int reg = 0; reg < 4; ++reg)
                    aux[nbase + quad * 4 + reg] =
                        make_float4(pq0[reg], pq1[reg], psd[reg], 0.f);
            }
        }
        __syncthreads();
    }
}

// ---------------- fused attention: 8 edges/wave, 8 lanes/edge, 8 channels/lane ----------------
// No online max: |alpha| is O(1) here (0.05-scale weights); softmax is shift-invariant.
__global__ __launch_bounds__(256) void attn_out(
        const __half* __restrict__ qh, const __half* __restrict__ kv,
        const float4* __restrict__ aux,
        const int2* __restrict__ edges, const int* __restrict__ rowptr,
        const float* __restrict__ wls, const float* __restrict__ consts,
        float* __restrict__ out, int Ntot) {
    const int lane = threadIdx.x & 63;
    const int grp = lane >> 3, t = lane & 7;
    const int n = blockIdx.x * 4 + (threadIdx.x >> 6);
    if (n >= Ntot) return;

    half8 q8 = *reinterpret_cast<const half8*>(qh + (size_t)n * 64 + 8 * t);
    half2v q2[4];
#pragma unroll
    for (int i = 0; i < 4; ++i) { q2[i][0] = q8[2 * i]; q2[i][1] = q8[2 * i + 1]; }
    float4 ax = aux[n];                 // {qe0, qe1, skipdot, -}
    const float qe0 = ax.x, qe1 = ax.y;

    const int p0 = rowptr[n], p1 = rowptr[n + 1];
    float l = 0.f, sx = 0.f, sy = 0.f;
    float acc[8] = {0.f,0.f,0.f,0.f,0.f,0.f,0.f,0.f};
    int p = p0;
    for (; p + 8 <= p1; p += 8) {                 // full batches: no masking
        int2 epk = edges[p + grp];
        int wbits = epk.y;
        float2 w = __half22float2(*reinterpret_cast<__half2*>(&wbits));
        const __half* kvp = kv + (size_t)epk.x * 128 + 8 * t;
        half8 k8 = *reinterpret_cast<const half8*>(kvp);
        half8 v8 = *reinterpret_cast<const half8*>(kvp + 64);
        const half2v* k2 = reinterpret_cast<const half2v*>(&k8);
        float prod = 0.f;
#pragma unroll
        for (int i = 0; i < 4; ++i) prod = DOT2(q2[i], k2[i], prod);
#pragma unroll
        for (int off = 1; off <= 4; off <<= 1) prod += __shfl_xor(prod, off, 64);
        float ex = __expf(fmaf(qe0, w.x, fmaf(qe1, w.y, prod)) * 0.125f);
        l += ex;
        sx = fmaf(ex, w.x, sx);
        sy = fmaf(ex, w.y, sy);
#pragma unroll
        for (int c = 0; c < 8; ++c) acc[c] = fmaf(ex, (float)v8[c], acc[c]);
    }
    if (p < p1) {                                  // tail batch: masked
        int pe = p + grp;
        bool act = pe < p1;
        int2 epk = edges[act ? pe : p0];
        int wbits = epk.y;
        float2 w = __half22float2(*reinterpret_cast<__half2*>(&wbits));
        const __half* kvp = kv + (size_t)epk.x * 128 + 8 * t;
        half8 k8 = *reinterpret_cast<const half8*>(kvp);
        half8 v8 = *reinterpret_cast<const half8*>(kvp + 64);
        const half2v* k2 = reinterpret_cast<const half2v*>(&k8);
        float prod = 0.f;
#pragma unroll
        for (int i = 0; i < 4; ++i) prod = DOT2(q2[i], k2[i], prod);
#pragma unroll
        for (int off = 1; off <= 4; off <<= 1) prod += __shfl_xor(prod, off, 64);
        float ex = act ? __expf(fmaf(qe0, w.x, fmaf(qe1, w.y, prod)) * 0.125f) : 0.f;
        l += ex;
        sx = fmaf(ex, w.x, sx);
        sy = fmaf(ex, w.y, sy);
#pragma unroll
        for (int c = 0; c < 8; ++c) acc[c] = fmaf(ex, (float)v8[c], acc[c]);
    }
    float4 wlsA = reinterpret_cast<const float4*>(wls)[2 * t];
    float4 wlsB = reinterpret_cast<const float4*>(wls)[2 * t + 1];
    float pd = acc[0] * wlsA.x + acc[1] * wlsA.y + acc[2] * wlsA.z + acc[3] * wlsA.w
             + acc[4] * wlsB.x + acc[5] * wlsB.y + acc[6] * wlsB.z + acc[7] * wlsB.w;
#pragma unroll
    for (int off = 1; off <= 32; off <<= 1) pd += __shfl_xor(pd, off, 64);
#pragma unroll
    for (int off = 8; off <= 32; off <<= 1) {      // across groups only
        l  += __shfl_xor(l,  off, 64);
        sx += __shfl_xor(sx, off, 64);
        sy += __shfl_xor(sy, off, 64);
    }
    if (lane == 0) {
        float inv_l = (l > 0.f) ? 1.f / l : 0.f;
        out[n] = inv_l * (pd + sx * consts[0] + sy * consts[1]) + ax.z + consts[2];
    }
}

// ---------------- launcher ----------------
extern "C" void kernel_launch(void* const* d_in, const int* in_sizes, int n_in,
                              void* d_out, int out_size, void* d_ws, size_t ws_size,
                              hipStream_t stream) {
    const float* x      = (const float*)d_in[0];
    const int*   ei     = (const int*)d_in[1];
    const float* ew     = (const float*)d_in[2];
    const float* conv_w = (const float*)d_in[6];
    const float* bn2_g  = (const float*)d_in[7];
    const float* bn2_b  = (const float*)d_in[8];
    const float* bn2_m  = (const float*)d_in[9];
    const float* bn2_v  = (const float*)d_in[10];
    const float* gcn_w  = (const float*)d_in[11];
    const float* gcn_b  = (const float*)d_in[12];
    const float* bn1_g  = (const float*)d_in[13];
    const float* bn1_b  = (const float*)d_in[14];
    const float* bn1_m  = (const float*)d_in[15];
    const float* bn1_v  = (const float*)d_in[16];
    const float* wq     = (const float*)d_in[17];
    const float* bq     = (const float*)d_in[18];
    const float* wk     = (const float*)d_in[19];
    const float* bk     = (const float*)d_in[20];
    const float* wv     = (const float*)d_in[21];
    const float* bv     = (const float*)d_in[22];
    const float* we     = (const float*)d_in[23];
    const float* wskip  = (const float*)d_in[24];
    const float* bskip  = (const float*)d_in[25];
    const float* wl     = (const float*)d_in[26];
    const float* bl     = (const float*)d_in[27];

    const int N = in_sizes[0] / CIN;     // 131072
    const int E = in_sizes[1] / 2;       // 1048576

    char* p = (char*)d_ws;
    auto alloc = [&](size_t bytes) {
        void* r = (void*)p;
        p += (bytes + 255) & ~(size_t)255;
        return r;
    };
    __half* wt16    = (__half*)alloc(36 * 64 * 8 * 2);
    float*  ebias   = (float*)alloc(64 * 4);
    __half* wlin    = (__half*)alloc(5 * 2 * 4 * 64 * 8 * 2);
    float*  wls     = (float*)alloc(64 * 4);
    float*  consts  = (float*)alloc(64 * 4);
    __half* bufA    = (__half*)alloc((size_t)N * 64 * 2);      // h0s fp16
    float*  bufB    = (float*)alloc((size_t)N * 64 * 4);       // kv fp16
    __half* bufQ    = (__half*)alloc((size_t)N * 64 * 2);      // q fp16
    __half* agg16   = (__half*)alloc((size_t)N * 64 * 2);      // agg fp16
    float4* aux     = (float4*)alloc((size_t)N * 16);          // {qe0,qe1,skipdot}
    float*  dinv    = (float*)alloc((size_t)N * 4);
    int*    cnt     = (int*)alloc((size_t)N * 4);
    unsigned short* rank = (unsigned short*)alloc((size_t)E * 2);
    int*    rowptr  = (int*)alloc((size_t)(N + 1) * 4);
    int2*   edges   = (int2*)alloc((size_t)E * 8);             // {row, half2 w}
    int*    bsum    = (int*)alloc(256 * 4);
    int*    boff    = (int*)alloc(256 * 4);

    __half* kv = (__half*)bufB;

    // ---- one-shot prep (cnt zero + all weight swizzles + attn consts) ----
    prep_all<<<(N + 255) / 256, 256, 0, stream>>>(
        conv_w, bn2_g, bn2_b, bn2_m, bn2_v,
        gcn_w, wq, wskip, wk, wv,
        bn1_g, bn1_b, bn1_m, bn1_v, wl, bl, we,
        wt16, ebias, wlin, wls, consts, cnt, N);

    // ---- CSR build (conv needs dinv) ----
    hist_kernel<<<(E + 255) / 256, 256, 0, stream>>>(ei + E, cnt, rank, E);
    scan1<<<N / 1024, 256, 0, stream>>>(cnt, bsum);
    scan2<<<1, 64, 0, stream>>>(bsum, boff, N / 1024);
    scan3<<<N / 1024, 256, 0, stream>>>(cnt, boff, rowptr, N);
    scatter_kernel<<<(E + 255) / 256, 256, 0, stream>>>(ei, ew, rank, rowptr, edges, E);
    deg_kernel<<<(N + 255) / 256, 256, 0, stream>>>(rowptr, edges, dinv, N);

    const int ngroups = N / 16;
    conv_mfma<<<ngroups / 16, 256, 0, stream>>>(x, wt16, ebias, dinv, bufA, ngroups);

    gcn_gather<<<(N + 3) / 4, 256, 0, stream>>>(bufA, edges, rowptr, dinv, agg16, N);

    mfma_fused<<<512, 256, 0, stream>>>(agg16, wlin, gcn_b,
                                        bn1_g, bn1_b, bn1_m, bn1_v,
                                        bq, bskip, bk, bv, wls, we,
                                        bufQ, kv, aux, ngroups);

    attn_out<<<(N + 3) / 4, 256, 0, stream>>>(bufQ, kv, aux, edges, rowptr,
                                              wls, consts, (float*)d_out, N);
}